// Round 10
// baseline (312.687 us; speedup 1.0000x reference)
//
#include <hip/hip_runtime.h>

typedef _Float16 half8  __attribute__((ext_vector_type(8)));
typedef _Float16 half4  __attribute__((ext_vector_type(4)));
typedef float    f32x4  __attribute__((ext_vector_type(4)));

#define MFMA32(a,b,c) __builtin_amdgcn_mfma_f32_16x16x32_f16(a,b,c,0,0,0)
#define MFMA16(a,b,c) __builtin_amdgcn_mfma_f32_16x16x16f16(a,b,c,0,0,0)

#if __has_builtin(__builtin_amdgcn_exp2f)
#define EXP2F(x) __builtin_amdgcn_exp2f(x)
#else
#define EXP2F(x) exp2f(x)
#endif

// Async global->LDS, 16B/lane, dest = wave-uniform base + lane*16.
// (round-3 post-mortem: per-lane reg staging of K/V doubled L1 transactions,
// -37%; GLOAD16+LDS redistribute is the right transport here.)
#define GLOAD16(gp, lp) __builtin_amdgcn_global_load_lds(                      \
    (const __attribute__((address_space(1))) void*)(gp),                       \
    (__attribute__((address_space(3))) void*)(lp), 16, 0, 0)

// scale = DH^-0.5 = 1/8, folded together with log2(e) into Q so softmax uses exp2.
static constexpr float SCALE_LOG2E = 0.18033688011112042f;

static constexpr size_t QH_OFF = 0;
static constexpr size_t KH_OFF = (size_t)8  << 20;
static constexpr size_t VT_OFF = (size_t)16 << 20;
static constexpr size_t LS_OFF = (size_t)24 << 20;
static constexpr size_t O_OFF  = (size_t)25 << 20;
static constexpr size_t LPART  = (size_t)4*8*2048;   // floats per m-half L partial
static constexpr size_t OPART  = (size_t)8192*512;   // halves per O partial

// Sb layout [A=n>>1][s=h+8*np][C=m]: GS=340 (A stride), 20 (s stride), C unit.
// (round-8, verified: write = 1 b64/t self-balancing, read = b16 broadcast,
// conflicts 1.68e7 -> 7.34e6.)
static constexpr int GS = 340;
// Wb layout [head][n][m]: round-9 change — n-stride 20 -> 22 (odd word-stride
// 11 after /2) and slab stride GSW=352. Old stride 20: write bank =
// (10(a+b3)+2qd)%32 -> 4-way; read bank = (10*l15+2qd)%32 -> 4-way. Stride 22:
// write bank = (10a+11*b3+2qd)%32 (odd term splits banks -> 2/bank, free);
// read bank = (11*l15+2qd)%32 (11 invertible mod 32 -> ~2/bank, free).
// Same instr count, same b64 alignment, +896 B LDS.
static constexpr int GSW  = 352;
static constexpr int WSTR = 22;

// ---------------------------------------------------------------------------
// K0a: X fp32 -> f16.  grid 4096 x 256 threads, 4 elems/thread.
// ---------------------------------------------------------------------------
__global__ __launch_bounds__(256)
void k_cvtx(const float* __restrict__ x, _Float16* __restrict__ xf)
{
  const size_t i = ((size_t)blockIdx.x*256 + threadIdx.x)*4;
  f32x4 v = *(const f32x4*)(x + i);
  half4 h;
#pragma unroll
  for (int j = 0; j < 4; j++) h[j] = (_Float16)v[j];
  *(half4*)(xf + i) = h;
}

// ---------------------------------------------------------------------------
// K0b: W fp32 [512k][1536c] -> f16 transposed Wt [1536c][512k]. LDS-tiled.
// ---------------------------------------------------------------------------
__global__ __launch_bounds__(256)
void k_cvtw(const float* __restrict__ w, _Float16* __restrict__ wt)
{
  __shared__ _Float16 T[32][36];
  const int kt = blockIdx.x, ct = blockIdx.y;
  const int r = threadIdx.x >> 3, c4 = (threadIdx.x & 7)*4;
  f32x4 v = *(const f32x4*)(w + (size_t)(kt*32 + r)*1536 + ct*32 + c4);
#pragma unroll
  for (int j = 0; j < 4; j++) T[r][c4 + j] = (_Float16)v[j];
  __syncthreads();
  half4 o;
#pragma unroll
  for (int j = 0; j < 4; j++) o[j] = T[c4 + j][r];
  *(half4*)(wt + (size_t)(ct*32 + r)*512 + kt*32 + c4) = o;
}

// ---------------------------------------------------------------------------
// K1: qkv projection, async-staged all-f16. C[8192,1536] = Xf @ Wt^T + b.
// ---------------------------------------------------------------------------
__global__ __launch_bounds__(256)
void k_qkv(const _Float16* __restrict__ xf, const _Float16* __restrict__ wt,
           const float* __restrict__ bias, _Float16* __restrict__ Qh,
           _Float16* __restrict__ Kh, _Float16* __restrict__ Vt)
{
  __shared__ __align__(16) _Float16 Xs[2048];   // 64 rows x 32 k
  __shared__ __align__(16) _Float16 Ws[2048];   // 64 cols x 32 k
  const int tid = threadIdx.x;
  const int wv = tid >> 6, lane = tid & 63, l15 = lane & 15, qd = lane >> 4;
  const int row0 = blockIdx.x * 64, col0 = blockIdx.y * 64;

  const int sslot = wv*64 + lane;
  const int sr = sslot >> 2, so = (sslot & 3) ^ ((sr >> 1) & 3);

  f32x4 acc[4] = {{0.f,0.f,0.f,0.f},{0.f,0.f,0.f,0.f},{0.f,0.f,0.f,0.f},{0.f,0.f,0.f,0.f}};

  for (int k0 = 0; k0 < 512; k0 += 32) {
    GLOAD16(xf + (size_t)(row0 + sr)*512 + k0 + so*8, &Xs[wv*512]);
    GLOAD16(wt + (size_t)(col0 + sr)*512 + k0 + so*8, &Ws[wv*512]);
    __syncthreads();
    const int ra = wv*16 + l15;
    half8 af = *(const half8*)&Xs[(ra*4 + (qd ^ ((ra >> 1) & 3)))*8];
#pragma unroll
    for (int ct = 0; ct < 4; ct++) {
      const int rb = ct*16 + l15;
      half8 bf = *(const half8*)&Ws[(rb*4 + (qd ^ ((rb >> 1) & 3)))*8];
      acc[ct] = MFMA32(af, bf, acc[ct]);
    }
    __syncthreads();
  }
#pragma unroll
  for (int ct = 0; ct < 4; ct++) {
    const int c = col0 + ct*16 + l15;
    const int sec = c >> 9, hh = (c >> 6) & 7, d = c & 63;
    const float bv = bias[c];
#pragma unroll
    for (int i = 0; i < 4; i++) {
      const int row = row0 + wv*16 + qd*4 + i;
      const int bb = row >> 11, n = row & 2047;
      float v = acc[ct][i] + bv;
      if (sec == 0)
        Qh[((size_t)((bb*8 + hh)*2048 + n))*64 + d] = (_Float16)(v * SCALE_LOG2E);
      else if (sec == 1)
        Kh[((size_t)((bb*8 + hh)*2048 + n))*64 + d] = (_Float16)v;
      else
        Vt[((size_t)((bb*8 + hh)*64 + d))*2048 + n] = (_Float16)v;
    }
  }
}

// ---------------------------------------------------------------------------
// K2: pass 1 — softmax denominators over an m-half. Grid 512 = 64nt x (4b x 2mh).
// Round-8 verified structure (swapped Sb layout).
// ---------------------------------------------------------------------------
__global__ __launch_bounds__(512, 4)
void k_pass1(const _Float16* __restrict__ Qh, const _Float16* __restrict__ Kh,
             const float* __restrict__ th1, float* __restrict__ Lsum)
{
  __shared__ __align__(16) _Float16 KB[8][1024];     // 16384 B
  __shared__ __align__(16) _Float16 Sb[2][2][2704];  // 21632 B
  const int tid = threadIdx.x;
  const int wv = tid >> 6, lane = tid & 63, l15 = lane & 15, qd = lane >> 4;
  const int s = blockIdx.x & 7, nt = blockIdx.x >> 3;
  const int b = s >> 1, mh = s & 1;
  const int n0 = nt << 5;
  const _Float16* kbase = Kh + ((size_t)((b*8 + wv)*2048 + mh*1024))*64;

  half4 a1f;
#pragma unroll
  for (int j = 0; j < 4; j++)
    a1f[j] = ((l15 >> 3) == (qd >> 1)) ? (_Float16)th1[(l15 & 7)*8 + (qd & 1)*4 + j]
                                       : (_Float16)0.f;

  half8 qf[2][2];
#pragma unroll
  for (int t = 0; t < 2; t++) {
    const _Float16* qp = Qh + ((size_t)((b*8 + wv)*2048 + n0 + t*16 + l15))*64 + qd*8;
    qf[t][0] = *(const half8*)qp;
    qf[t][1] = *(const half8*)(qp + 32);
  }

  auto issueK = [&](int it) {
#pragma unroll
    for (int j = 0; j < 2; j++) {
      const int bk = j*64 + lane;
      const int m = bk >> 3, c = bk & 7;
      const int cp = c ^ (m & 7);
      GLOAD16(kbase + (size_t)(it*16 + m)*64 + cp*8, &KB[wv][j*512]);
    }
  };
  // swapped layout: one b64 write per t at [A=l15>>1][s=wv+8*(l15&1)][C=qd*4]
  auto qk_to_sb = [&](int buf) {
    half8 ka0 = *(const half8*)&KB[wv][l15*64 + ((qd       ^ (l15 & 7))*8)];
    half8 ka1 = *(const half8*)&KB[wv][l15*64 + (((4 + qd) ^ (l15 & 7))*8)];
#pragma unroll
    for (int t = 0; t < 2; t++) {
      f32x4 a = {0.f,0.f,0.f,0.f};
      a = MFMA32(ka0, qf[t][0], a);
      a = MFMA32(ka1, qf[t][1], a);
      half4 s4;
#pragma unroll
      for (int i = 0; i < 4; i++) s4[i] = (_Float16)a[i];
      *(half4*)&Sb[buf][t][(l15 >> 1)*GS + (wv + 8*(l15 & 1))*20 + qd*4] = s4;
    }
  };

  float lacc[2][4];
#pragma unroll
  for (int t = 0; t < 2; t++)
#pragma unroll
    for (int i = 0; i < 4; i++) lacc[t][i] = 0.f;

  issueK(0);
  __syncthreads();
  for (int it = 0; it <= 64; it++) {
    if (it < 64) {
      qk_to_sb(it & 1);
      if (it + 1 < 64) issueK(it + 1);
    }
    if (it >= 1) {
      const int buf = (it - 1) & 1;
#pragma unroll
      for (int t = 0; t < 2; t++) {
        half4 b1;
#pragma unroll
        for (int j = 0; j < 4; j++)
          b1[j] = Sb[buf][t][wv*GS + (qd*4 + j)*20 + l15];
        f32x4 c1 = MFMA16(a1f, b1, ((f32x4){0.f,0.f,0.f,0.f}));
#pragma unroll
        for (int i = 0; i < 4; i++) lacc[t][i] += EXP2F(c1[i]);
      }
    }
    __syncthreads();
  }

#pragma unroll
  for (int t = 0; t < 2; t++)
#pragma unroll
    for (int i = 0; i < 4; i++) {
      float v = lacc[t][i];
      v += __shfl_xor(v, 1); v += __shfl_xor(v, 2);
      v += __shfl_xor(v, 4); v += __shfl_xor(v, 8);
      lacc[t][i] = v;
    }
  if (l15 == 0) {
#pragma unroll
    for (int t = 0; t < 2; t++)
#pragma unroll
      for (int i = 0; i < 4; i++) {
        const int n = n0 + t*16 + wv*2 + (qd >> 1);
        const int g = (qd & 1)*4 + i;
        Lsum[(size_t)mh*LPART + (size_t)(b*8 + g)*2048 + n] = lacc[t][i];
      }
  }
}

// ---------------------------------------------------------------------------
// K3: pass 2 over an m-half. Round-8 verified structure + Wb stride 20->22
// (GSW=352) to kill the remaining 4-way write/read conflicts (see constants).
// ---------------------------------------------------------------------------
__global__ __launch_bounds__(512, 4)
void k_pass2(const _Float16* __restrict__ Qh, const _Float16* __restrict__ Kh,
             const _Float16* __restrict__ Vt, const float* __restrict__ Lsum,
             const float* __restrict__ th1, const float* __restrict__ th2,
             _Float16* __restrict__ Obuf)
{
  __shared__ __align__(16) _Float16 KB[8][1024];     // 16384 B
  __shared__ __align__(16) _Float16 VB[8][1024];     // 16384 B [wv][slot=mh2*64+d]
  __shared__ __align__(16) _Float16 Sb[2][2][2704];  // 21632 B
  __shared__ __align__(16) _Float16 Wb[2][2][2816];  // 22528 B  (total 76928 B)
  const int tid = threadIdx.x;
  const int wv = tid >> 6, lane = tid & 63, l15 = lane & 15, qd = lane >> 4;
  const int s = blockIdx.x & 7, nt = blockIdx.x >> 3;
  const int b = s >> 1, mh = s & 1;
  const int n0 = nt << 5;
  const _Float16* kbase = Kh + ((size_t)((b*8 + wv)*2048 + mh*1024))*64;
  const _Float16* vbase = Vt + (size_t)(b*8 + wv)*64*2048 + mh*1024;

  half4 a1f, b2f;
#pragma unroll
  for (int j = 0; j < 4; j++) {
    const bool diag = ((l15 >> 3) == (qd >> 1));
    a1f[j] = diag ? (_Float16)th1[(l15 & 7)*8 + (qd & 1)*4 + j] : (_Float16)0.f;
    b2f[j] = diag ? (_Float16)th2[(l15 & 7)*8 + (qd & 1)*4 + j] : (_Float16)0.f;
  }

  // softmax seed, hoisted to registers (constant per lane across all iters)
  f32x4 cs[2];
#pragma unroll
  for (int t = 0; t < 2; t++)
#pragma unroll
    for (int i = 0; i < 4; i++) {
      const int n = n0 + t*16 + wv*2 + (qd >> 1);
      const int g = (qd & 1)*4 + i;
      const size_t off = (size_t)(b*8 + g)*2048 + n;
      cs[t][i] = -__log2f(Lsum[off] + Lsum[off + LPART]);
    }

  half8 qf[2][2];
#pragma unroll
  for (int t = 0; t < 2; t++) {
    const _Float16* qp = Qh + ((size_t)((b*8 + wv)*2048 + n0 + t*16 + l15))*64 + qd*8;
    qf[t][0] = *(const half8*)qp;
    qf[t][1] = *(const half8*)(qp + 32);
  }

  auto issueK = [&](int it) {
#pragma unroll
    for (int j = 0; j < 2; j++) {
      const int bk = j*64 + lane;
      const int m = bk >> 3, c = bk & 7;
      const int cp = c ^ (m & 7);
      GLOAD16(kbase + (size_t)(it*16 + m)*64 + cp*8, &KB[wv][j*512]);
    }
  };
  // VB slots: issue j covers slots j*64+lane = (mhalf=j, d=lane)
  auto issueV = [&](int it) {
#pragma unroll
    for (int j = 0; j < 2; j++)
      GLOAD16(vbase + (size_t)lane*2048 + it*16 + j*8, &VB[wv][j*512]);
  };
  // swapped layout: one b64 write per t (see k_pass1)
  auto qk_to_sb = [&](int buf) {
    half8 ka0 = *(const half8*)&KB[wv][l15*64 + ((qd       ^ (l15 & 7))*8)];
    half8 ka1 = *(const half8*)&KB[wv][l15*64 + (((4 + qd) ^ (l15 & 7))*8)];
#pragma unroll
    for (int t = 0; t < 2; t++) {
      f32x4 a = {0.f,0.f,0.f,0.f};
      a = MFMA32(ka0, qf[t][0], a);
      a = MFMA32(ka1, qf[t][1], a);
      half4 s4;
#pragma unroll
      for (int i = 0; i < 4; i++) s4[i] = (_Float16)a[i];
      *(half4*)&Sb[buf][t][(l15 >> 1)*GS + (wv + 8*(l15 & 1))*20 + qd*4] = s4;
    }
  };

  f32x4 og[2][4];
#pragma unroll
  for (int t = 0; t < 2; t++)
#pragma unroll
    for (int dt = 0; dt < 4; dt++)
      og[t][dt] = (f32x4){0.f,0.f,0.f,0.f};

  issueK(0);
  __syncthreads();

  for (int it = 0; it <= 65; it++) {
    if (it < 64) {
      qk_to_sb(it & 1);
      if (it + 1 < 64) issueK(it + 1);
    }

    if (it >= 1 && it <= 64) {
      const int buf = (it - 1) & 1;
#pragma unroll
      for (int t = 0; t < 2; t++) {
        half4 b1;
#pragma unroll
        for (int j = 0; j < 4; j++)
          b1[j] = Sb[buf][t][wv*GS + (qd*4 + j)*20 + l15];
        f32x4 c1 = MFMA16(a1f, b1, cs[t]);
        half4 a2;
#pragma unroll
        for (int i = 0; i < 4; i++) a2[i] = (_Float16)EXP2F(c1[i]);
        f32x4 c2 = MFMA16(a2, b2f, ((f32x4){0.f,0.f,0.f,0.f}));
        half4 w4;
#pragma unroll
        for (int i = 0; i < 4; i++) w4[i] = (_Float16)c2[i];
        *(half4*)&Wb[buf][t][(l15 & 7)*GSW + (wv*2 + (l15 >> 3))*WSTR + qd*4] = w4;
      }
    }
    if (it >= 2) {
      const int buf = (it - 2) & 1;
      half4 vb[4];
#pragma unroll
      for (int dt = 0; dt < 4; dt++)
        vb[dt] = *(const half4*)&VB[wv][((qd >> 1)*64 + dt*16 + l15)*8 + (qd & 1)*4];
#pragma unroll
      for (int t = 0; t < 2; t++) {
        half4 af = *(const half4*)&Wb[buf][t][wv*GSW + l15*WSTR + qd*4];
#pragma unroll
        for (int dt = 0; dt < 4; dt++)
          og[t][dt] = MFMA16(af, vb[dt], og[t][dt]);
      }
    }
    if (it >= 1 && it <= 64) issueV(it - 1);   // after VB reads (in-wave WAR safe)
    __syncthreads();
  }

  // epilogue: og[t][dt][i] -> (n = n0+t*16+qd*4+i, col = wv*64 + dt*16 + l15)
  _Float16* Op = Obuf + (size_t)mh * OPART + ((size_t)(b*2048 + n0))*512;
#pragma unroll
  for (int t = 0; t < 2; t++)
#pragma unroll
    for (int dt = 0; dt < 4; dt++)
#pragma unroll
      for (int i = 0; i < 4; i++)
        Op[(size_t)(t*16 + qd*4 + i)*512 + wv*64 + dt*16 + l15] = (_Float16)og[t][dt][i];
}

// ---------------------------------------------------------------------------
// K4: output projection summing 2 partial O buffers.
// out[8192,512] = (O0+O1) @ w_out[512,512] + b_out (fp32 out)
// ---------------------------------------------------------------------------
__global__ __launch_bounds__(256)
void k_oproj(const _Float16* __restrict__ Ob, const float* __restrict__ w,
             const float* __restrict__ bias, float* __restrict__ out)
{
  __shared__ __align__(16) _Float16 Xs[64*40];
  __shared__ __align__(16) _Float16 Wt[64*40];
  const int tid = threadIdx.x;
  const int wv = tid >> 6, lane = tid & 63, l15 = lane & 15, qd = lane >> 4;
  const int row0 = blockIdx.x * 64, col0 = blockIdx.y * 64;
  const int xr = tid >> 2, xc = (tid & 3) * 8;
  const int wk = tid >> 3, wc = (tid & 7) * 8;

  f32x4 acc[4] = {{0.f,0.f,0.f,0.f},{0.f,0.f,0.f,0.f},{0.f,0.f,0.f,0.f},{0.f,0.f,0.f,0.f}};

  for (int k0 = 0; k0 < 512; k0 += 32) {
    const size_t idx = (size_t)(row0 + xr)*512 + k0 + xc;
    half8 a0 = *(const half8*)(Ob + idx);
    half8 a1 = *(const half8*)(Ob + OPART + idx);
    *(half8*)&Xs[xr*40 + xc] = a0 + a1;
    f32x4 b0 = *(const f32x4*)(w + (size_t)(k0 + wk)*512 + col0 + wc);
    f32x4 b1 = *(const f32x4*)(w + (size_t)(k0 + wk)*512 + col0 + wc + 4);
#pragma unroll
    for (int j = 0; j < 4; j++) {
      Wt[(wc+j  )*40 + wk] = (_Float16)b0[j];
      Wt[(wc+j+4)*40 + wk] = (_Float16)b1[j];
    }
    __syncthreads();
    half8 af = *(const half8*)&Xs[(wv*16 + l15)*40 + qd*8];
#pragma unroll
    for (int ct = 0; ct < 4; ct++) {
      half8 bf = *(const half8*)&Wt[(ct*16 + l15)*40 + qd*8];
      acc[ct] = MFMA32(af, bf, acc[ct]);
    }
    __syncthreads();
  }
#pragma unroll
  for (int ct = 0; ct < 4; ct++) {
    const int c = col0 + ct*16 + l15;
    const float bv = bias[c];
#pragma unroll
    for (int i = 0; i < 4; i++) {
      const int row = row0 + wv*16 + qd*4 + i;
      out[(size_t)row*512 + c] = acc[ct][i] + bv;
    }
  }
}

// ---------------------------------------------------------------------------
extern "C" void kernel_launch(void* const* d_in, const int* in_sizes, int n_in,
                              void* d_out, int out_size, void* d_ws, size_t ws_size,
                              hipStream_t stream)
{
  (void)in_sizes; (void)n_in; (void)out_size;
  const float* x     = (const float*)d_in[0];
  const float* w_qkv = (const float*)d_in[1];
  const float* b_qkv = (const float*)d_in[2];
  const float* th1   = (const float*)d_in[3];
  const float* th2   = (const float*)d_in[4];
  const float* w_out = (const float*)d_in[5];
  const float* b_out = (const float*)d_in[6];
  float* out = (float*)d_out;

  char* ws = (char*)d_ws;
  _Float16* Qh   = (_Float16*)(ws + QH_OFF);
  _Float16* Kh   = (_Float16*)(ws + KH_OFF);
  _Float16* Vt   = (_Float16*)(ws + VT_OFF);
  float*    Lsum = (float*)   (ws + LS_OFF);
  _Float16* Obuf = (_Float16*)(ws + O_OFF);
  // Xf/Wtf alias the Obuf region (qkv consumes them before pass2 writes O)
  _Float16* Xf   = (_Float16*)(ws + O_OFF);
  _Float16* Wtf  = (_Float16*)(ws + O_OFF + ((size_t)8 << 20));
  if (ws_size < ((size_t)41 << 20)) return;  // need 41 MB scratch

  k_cvtx <<<dim3(4096),    256, 0, stream>>>(x, Xf);
  k_cvtw <<<dim3(16, 48),  256, 0, stream>>>(w_qkv, Wtf);
  k_qkv  <<<dim3(128, 24), 256, 0, stream>>>(Xf, Wtf, b_qkv, Qh, Kh, Vt);
  k_pass1<<<dim3(512),     512, 0, stream>>>(Qh, Kh, th1, Lsum);
  k_pass2<<<dim3(512),     512, 0, stream>>>(Qh, Kh, Vt, Lsum, th1, th2, Obuf);
  k_oproj<<<dim3(128, 8),  256, 0, stream>>>(Obuf, w_out, b_out, out);
}

// Round 11
// 303.266 us; speedup vs baseline: 1.0311x; 1.0311x over previous
//
#include <hip/hip_runtime.h>

typedef _Float16 half8  __attribute__((ext_vector_type(8)));
typedef _Float16 half4  __attribute__((ext_vector_type(4)));
typedef float    f32x4  __attribute__((ext_vector_type(4)));

#define MFMA32(a,b,c) __builtin_amdgcn_mfma_f32_16x16x32_f16(a,b,c,0,0,0)
#define MFMA16(a,b,c) __builtin_amdgcn_mfma_f32_16x16x16f16(a,b,c,0,0,0)

#if __has_builtin(__builtin_amdgcn_exp2f)
#define EXP2F(x) __builtin_amdgcn_exp2f(x)
#else
#define EXP2F(x) exp2f(x)
#endif

// Async global->LDS, 16B/lane, dest = wave-uniform base + lane*16.
// (round-3 post-mortem: per-lane reg staging of K/V doubled L1 transactions,
// -37%; GLOAD16+LDS redistribute is the right transport here.)
#define GLOAD16(gp, lp) __builtin_amdgcn_global_load_lds(                      \
    (const __attribute__((address_space(1))) void*)(gp),                       \
    (__attribute__((address_space(3))) void*)(lp), 16, 0, 0)

// scale = DH^-0.5 = 1/8, folded together with log2(e) into Q so softmax uses exp2.
static constexpr float SCALE_LOG2E = 0.18033688011112042f;

static constexpr size_t QH_OFF = 0;
static constexpr size_t KH_OFF = (size_t)8  << 20;
static constexpr size_t VT_OFF = (size_t)16 << 20;
static constexpr size_t LS_OFF = (size_t)24 << 20;
static constexpr size_t O_OFF  = (size_t)25 << 20;
static constexpr size_t LPART  = (size_t)4*8*2048;   // floats per m-half L partial
static constexpr size_t OPART  = (size_t)8192*512;   // halves per O partial

// Sb layout [A=n>>1][s=h+8*np][C=m]: GS=340 (A stride), 20 (s stride), C unit.
// (round-8, verified: write b64 = 16 even banks x4 = floor; read b16 word-
// coalesced all-32-banks = floor. conflicts 1.68e7 -> 7.34e6.)
static constexpr int GS = 340;
// Wb (round-11): linear [g:8][npair:16][m:16] halves (g*256 + npair*16 + m)
// with XOR swizzle: physical = linear ^ ((g&3)<<4). ROUND-10 ERRATUM: stride
// 22 made write bank = 16*(a&1)+11*b3+2qd (176 words == 16 mod 32, head term
// parity-degenerate) -> 2x floor, conflicts UP 71%. The XOR form is exact:
// write bank = 8*((npair&3)^(g&3)) + 2qd -> 4 lanes/bank = b64 floor;
// read  bank = 8*((l15&3)^(wv&3))  + 2qd -> 4 lanes/bank = b64 floor.
// All other LDS accesses (Sb, KB b128, VB b64, GLOAD writes) audit to floor.
// Bonus: Wb shrinks 22528 -> 16384 B.

// ---------------------------------------------------------------------------
// K0a: X fp32 -> f16.  grid 4096 x 256 threads, 4 elems/thread.
// ---------------------------------------------------------------------------
__global__ __launch_bounds__(256)
void k_cvtx(const float* __restrict__ x, _Float16* __restrict__ xf)
{
  const size_t i = ((size_t)blockIdx.x*256 + threadIdx.x)*4;
  f32x4 v = *(const f32x4*)(x + i);
  half4 h;
#pragma unroll
  for (int j = 0; j < 4; j++) h[j] = (_Float16)v[j];
  *(half4*)(xf + i) = h;
}

// ---------------------------------------------------------------------------
// K0b: W fp32 [512k][1536c] -> f16 transposed Wt [1536c][512k]. LDS-tiled.
// ---------------------------------------------------------------------------
__global__ __launch_bounds__(256)
void k_cvtw(const float* __restrict__ w, _Float16* __restrict__ wt)
{
  __shared__ _Float16 T[32][36];
  const int kt = blockIdx.x, ct = blockIdx.y;
  const int r = threadIdx.x >> 3, c4 = (threadIdx.x & 7)*4;
  f32x4 v = *(const f32x4*)(w + (size_t)(kt*32 + r)*1536 + ct*32 + c4);
#pragma unroll
  for (int j = 0; j < 4; j++) T[r][c4 + j] = (_Float16)v[j];
  __syncthreads();
  half4 o;
#pragma unroll
  for (int j = 0; j < 4; j++) o[j] = T[c4 + j][r];
  *(half4*)(wt + (size_t)(ct*32 + r)*512 + kt*32 + c4) = o;
}

// ---------------------------------------------------------------------------
// K1: qkv projection, async-staged all-f16. C[8192,1536] = Xf @ Wt^T + b.
// ---------------------------------------------------------------------------
__global__ __launch_bounds__(256)
void k_qkv(const _Float16* __restrict__ xf, const _Float16* __restrict__ wt,
           const float* __restrict__ bias, _Float16* __restrict__ Qh,
           _Float16* __restrict__ Kh, _Float16* __restrict__ Vt)
{
  __shared__ __align__(16) _Float16 Xs[2048];   // 64 rows x 32 k
  __shared__ __align__(16) _Float16 Ws[2048];   // 64 cols x 32 k
  const int tid = threadIdx.x;
  const int wv = tid >> 6, lane = tid & 63, l15 = lane & 15, qd = lane >> 4;
  const int row0 = blockIdx.x * 64, col0 = blockIdx.y * 64;

  const int sslot = wv*64 + lane;
  const int sr = sslot >> 2, so = (sslot & 3) ^ ((sr >> 1) & 3);

  f32x4 acc[4] = {{0.f,0.f,0.f,0.f},{0.f,0.f,0.f,0.f},{0.f,0.f,0.f,0.f},{0.f,0.f,0.f,0.f}};

  for (int k0 = 0; k0 < 512; k0 += 32) {
    GLOAD16(xf + (size_t)(row0 + sr)*512 + k0 + so*8, &Xs[wv*512]);
    GLOAD16(wt + (size_t)(col0 + sr)*512 + k0 + so*8, &Ws[wv*512]);
    __syncthreads();
    const int ra = wv*16 + l15;
    half8 af = *(const half8*)&Xs[(ra*4 + (qd ^ ((ra >> 1) & 3)))*8];
#pragma unroll
    for (int ct = 0; ct < 4; ct++) {
      const int rb = ct*16 + l15;
      half8 bf = *(const half8*)&Ws[(rb*4 + (qd ^ ((rb >> 1) & 3)))*8];
      acc[ct] = MFMA32(af, bf, acc[ct]);
    }
    __syncthreads();
  }
#pragma unroll
  for (int ct = 0; ct < 4; ct++) {
    const int c = col0 + ct*16 + l15;
    const int sec = c >> 9, hh = (c >> 6) & 7, d = c & 63;
    const float bv = bias[c];
#pragma unroll
    for (int i = 0; i < 4; i++) {
      const int row = row0 + wv*16 + qd*4 + i;
      const int bb = row >> 11, n = row & 2047;
      float v = acc[ct][i] + bv;
      if (sec == 0)
        Qh[((size_t)((bb*8 + hh)*2048 + n))*64 + d] = (_Float16)(v * SCALE_LOG2E);
      else if (sec == 1)
        Kh[((size_t)((bb*8 + hh)*2048 + n))*64 + d] = (_Float16)v;
      else
        Vt[((size_t)((bb*8 + hh)*64 + d))*2048 + n] = (_Float16)v;
    }
  }
}

// ---------------------------------------------------------------------------
// K2: pass 1 — softmax denominators over an m-half. Grid 512 = 64nt x (4b x 2mh).
// Round-8 verified structure (swapped Sb layout).
// ---------------------------------------------------------------------------
__global__ __launch_bounds__(512, 4)
void k_pass1(const _Float16* __restrict__ Qh, const _Float16* __restrict__ Kh,
             const float* __restrict__ th1, float* __restrict__ Lsum)
{
  __shared__ __align__(16) _Float16 KB[8][1024];     // 16384 B
  __shared__ __align__(16) _Float16 Sb[2][2][2704];  // 21632 B
  const int tid = threadIdx.x;
  const int wv = tid >> 6, lane = tid & 63, l15 = lane & 15, qd = lane >> 4;
  const int s = blockIdx.x & 7, nt = blockIdx.x >> 3;
  const int b = s >> 1, mh = s & 1;
  const int n0 = nt << 5;
  const _Float16* kbase = Kh + ((size_t)((b*8 + wv)*2048 + mh*1024))*64;

  half4 a1f;
#pragma unroll
  for (int j = 0; j < 4; j++)
    a1f[j] = ((l15 >> 3) == (qd >> 1)) ? (_Float16)th1[(l15 & 7)*8 + (qd & 1)*4 + j]
                                       : (_Float16)0.f;

  half8 qf[2][2];
#pragma unroll
  for (int t = 0; t < 2; t++) {
    const _Float16* qp = Qh + ((size_t)((b*8 + wv)*2048 + n0 + t*16 + l15))*64 + qd*8;
    qf[t][0] = *(const half8*)qp;
    qf[t][1] = *(const half8*)(qp + 32);
  }

  auto issueK = [&](int it) {
#pragma unroll
    for (int j = 0; j < 2; j++) {
      const int bk = j*64 + lane;
      const int m = bk >> 3, c = bk & 7;
      const int cp = c ^ (m & 7);
      GLOAD16(kbase + (size_t)(it*16 + m)*64 + cp*8, &KB[wv][j*512]);
    }
  };
  // swapped layout: one b64 write per t at [A=l15>>1][s=wv+8*(l15&1)][C=qd*4]
  auto qk_to_sb = [&](int buf) {
    half8 ka0 = *(const half8*)&KB[wv][l15*64 + ((qd       ^ (l15 & 7))*8)];
    half8 ka1 = *(const half8*)&KB[wv][l15*64 + (((4 + qd) ^ (l15 & 7))*8)];
#pragma unroll
    for (int t = 0; t < 2; t++) {
      f32x4 a = {0.f,0.f,0.f,0.f};
      a = MFMA32(ka0, qf[t][0], a);
      a = MFMA32(ka1, qf[t][1], a);
      half4 s4;
#pragma unroll
      for (int i = 0; i < 4; i++) s4[i] = (_Float16)a[i];
      *(half4*)&Sb[buf][t][(l15 >> 1)*GS + (wv + 8*(l15 & 1))*20 + qd*4] = s4;
    }
  };

  float lacc[2][4];
#pragma unroll
  for (int t = 0; t < 2; t++)
#pragma unroll
    for (int i = 0; i < 4; i++) lacc[t][i] = 0.f;

  issueK(0);
  __syncthreads();
  for (int it = 0; it <= 64; it++) {
    if (it < 64) {
      qk_to_sb(it & 1);
      if (it + 1 < 64) issueK(it + 1);
    }
    if (it >= 1) {
      const int buf = (it - 1) & 1;
#pragma unroll
      for (int t = 0; t < 2; t++) {
        half4 b1;
#pragma unroll
        for (int j = 0; j < 4; j++)
          b1[j] = Sb[buf][t][wv*GS + (qd*4 + j)*20 + l15];
        f32x4 c1 = MFMA16(a1f, b1, ((f32x4){0.f,0.f,0.f,0.f}));
#pragma unroll
        for (int i = 0; i < 4; i++) lacc[t][i] += EXP2F(c1[i]);
      }
    }
    __syncthreads();
  }

#pragma unroll
  for (int t = 0; t < 2; t++)
#pragma unroll
    for (int i = 0; i < 4; i++) {
      float v = lacc[t][i];
      v += __shfl_xor(v, 1); v += __shfl_xor(v, 2);
      v += __shfl_xor(v, 4); v += __shfl_xor(v, 8);
      lacc[t][i] = v;
    }
  if (l15 == 0) {
#pragma unroll
    for (int t = 0; t < 2; t++)
#pragma unroll
      for (int i = 0; i < 4; i++) {
        const int n = n0 + t*16 + wv*2 + (qd >> 1);
        const int g = (qd & 1)*4 + i;
        Lsum[(size_t)mh*LPART + (size_t)(b*8 + g)*2048 + n] = lacc[t][i];
      }
  }
}

// ---------------------------------------------------------------------------
// K3: pass 2 over an m-half. Round-8 verified structure + XOR-swizzled Wb
// (floor-banked both sides; see constants comment).
// ---------------------------------------------------------------------------
__global__ __launch_bounds__(512, 4)
void k_pass2(const _Float16* __restrict__ Qh, const _Float16* __restrict__ Kh,
             const _Float16* __restrict__ Vt, const float* __restrict__ Lsum,
             const float* __restrict__ th1, const float* __restrict__ th2,
             _Float16* __restrict__ Obuf)
{
  __shared__ __align__(16) _Float16 KB[8][1024];     // 16384 B
  __shared__ __align__(16) _Float16 VB[8][1024];     // 16384 B [wv][slot=mh2*64+d]
  __shared__ __align__(16) _Float16 Sb[2][2][2704];  // 21632 B
  __shared__ __align__(16) _Float16 Wb[2][2][2048];  // 16384 B  (total 70784 B)
  const int tid = threadIdx.x;
  const int wv = tid >> 6, lane = tid & 63, l15 = lane & 15, qd = lane >> 4;
  const int s = blockIdx.x & 7, nt = blockIdx.x >> 3;
  const int b = s >> 1, mh = s & 1;
  const int n0 = nt << 5;
  const _Float16* kbase = Kh + ((size_t)((b*8 + wv)*2048 + mh*1024))*64;
  const _Float16* vbase = Vt + (size_t)(b*8 + wv)*64*2048 + mh*1024;

  half4 a1f, b2f;
#pragma unroll
  for (int j = 0; j < 4; j++) {
    const bool diag = ((l15 >> 3) == (qd >> 1));
    a1f[j] = diag ? (_Float16)th1[(l15 & 7)*8 + (qd & 1)*4 + j] : (_Float16)0.f;
    b2f[j] = diag ? (_Float16)th2[(l15 & 7)*8 + (qd & 1)*4 + j] : (_Float16)0.f;
  }

  // softmax seed, hoisted to registers (constant per lane across all iters)
  f32x4 cs[2];
#pragma unroll
  for (int t = 0; t < 2; t++)
#pragma unroll
    for (int i = 0; i < 4; i++) {
      const int n = n0 + t*16 + wv*2 + (qd >> 1);
      const int g = (qd & 1)*4 + i;
      const size_t off = (size_t)(b*8 + g)*2048 + n;
      cs[t][i] = -__log2f(Lsum[off] + Lsum[off + LPART]);
    }

  half8 qf[2][2];
#pragma unroll
  for (int t = 0; t < 2; t++) {
    const _Float16* qp = Qh + ((size_t)((b*8 + wv)*2048 + n0 + t*16 + l15))*64 + qd*8;
    qf[t][0] = *(const half8*)qp;
    qf[t][1] = *(const half8*)(qp + 32);
  }

  auto issueK = [&](int it) {
#pragma unroll
    for (int j = 0; j < 2; j++) {
      const int bk = j*64 + lane;
      const int m = bk >> 3, c = bk & 7;
      const int cp = c ^ (m & 7);
      GLOAD16(kbase + (size_t)(it*16 + m)*64 + cp*8, &KB[wv][j*512]);
    }
  };
  // VB slots: issue j covers slots j*64+lane = (mhalf=j, d=lane)
  auto issueV = [&](int it) {
#pragma unroll
    for (int j = 0; j < 2; j++)
      GLOAD16(vbase + (size_t)lane*2048 + it*16 + j*8, &VB[wv][j*512]);
  };
  // swapped layout: one b64 write per t (see k_pass1)
  auto qk_to_sb = [&](int buf) {
    half8 ka0 = *(const half8*)&KB[wv][l15*64 + ((qd       ^ (l15 & 7))*8)];
    half8 ka1 = *(const half8*)&KB[wv][l15*64 + (((4 + qd) ^ (l15 & 7))*8)];
#pragma unroll
    for (int t = 0; t < 2; t++) {
      f32x4 a = {0.f,0.f,0.f,0.f};
      a = MFMA32(ka0, qf[t][0], a);
      a = MFMA32(ka1, qf[t][1], a);
      half4 s4;
#pragma unroll
      for (int i = 0; i < 4; i++) s4[i] = (_Float16)a[i];
      *(half4*)&Sb[buf][t][(l15 >> 1)*GS + (wv + 8*(l15 & 1))*20 + qd*4] = s4;
    }
  };

  // Wb XOR-swizzled addresses (g*256 + npair*16 + m) ^ ((g&3)<<4)
  const int wb_wr = (((l15 & 7)*256 + (wv*2 + (l15 >> 3))*16 + qd*4) ^ ((l15 & 3) << 4));
  const int wb_rd = ((wv*256 + l15*16 + qd*4) ^ ((wv & 3) << 4));

  f32x4 og[2][4];
#pragma unroll
  for (int t = 0; t < 2; t++)
#pragma unroll
    for (int dt = 0; dt < 4; dt++)
      og[t][dt] = (f32x4){0.f,0.f,0.f,0.f};

  issueK(0);
  __syncthreads();

  for (int it = 0; it <= 65; it++) {
    if (it < 64) {
      qk_to_sb(it & 1);
      if (it + 1 < 64) issueK(it + 1);
    }

    if (it >= 1 && it <= 64) {
      const int buf = (it - 1) & 1;
#pragma unroll
      for (int t = 0; t < 2; t++) {
        half4 b1;
#pragma unroll
        for (int j = 0; j < 4; j++)
          b1[j] = Sb[buf][t][wv*GS + (qd*4 + j)*20 + l15];
        f32x4 c1 = MFMA16(a1f, b1, cs[t]);
        half4 a2;
#pragma unroll
        for (int i = 0; i < 4; i++) a2[i] = (_Float16)EXP2F(c1[i]);
        f32x4 c2 = MFMA16(a2, b2f, ((f32x4){0.f,0.f,0.f,0.f}));
        half4 w4;
#pragma unroll
        for (int i = 0; i < 4; i++) w4[i] = (_Float16)c2[i];
        *(half4*)&Wb[buf][t][wb_wr] = w4;
      }
    }
    if (it >= 2) {
      const int buf = (it - 2) & 1;
      half4 vb[4];
#pragma unroll
      for (int dt = 0; dt < 4; dt++)
        vb[dt] = *(const half4*)&VB[wv][((qd >> 1)*64 + dt*16 + l15)*8 + (qd & 1)*4];
#pragma unroll
      for (int t = 0; t < 2; t++) {
        half4 af = *(const half4*)&Wb[buf][t][wb_rd];
#pragma unroll
        for (int dt = 0; dt < 4; dt++)
          og[t][dt] = MFMA16(af, vb[dt], og[t][dt]);
      }
    }
    if (it >= 1 && it <= 64) issueV(it - 1);   // after VB reads (in-wave WAR safe)
    __syncthreads();
  }

  // epilogue: og[t][dt][i] -> (n = n0+t*16+qd*4+i, col = wv*64 + dt*16 + l15)
  _Float16* Op = Obuf + (size_t)mh * OPART + ((size_t)(b*2048 + n0))*512;
#pragma unroll
  for (int t = 0; t < 2; t++)
#pragma unroll
    for (int dt = 0; dt < 4; dt++)
#pragma unroll
      for (int i = 0; i < 4; i++)
        Op[(size_t)(t*16 + qd*4 + i)*512 + wv*64 + dt*16 + l15] = (_Float16)og[t][dt][i];
}

// ---------------------------------------------------------------------------
// K4: output projection summing 2 partial O buffers.
// out[8192,512] = (O0+O1) @ w_out[512,512] + b_out (fp32 out)
// ---------------------------------------------------------------------------
__global__ __launch_bounds__(256)
void k_oproj(const _Float16* __restrict__ Ob, const float* __restrict__ w,
             const float* __restrict__ bias, float* __restrict__ out)
{
  __shared__ __align__(16) _Float16 Xs[64*40];
  __shared__ __align__(16) _Float16 Wt[64*40];
  const int tid = threadIdx.x;
  const int wv = tid >> 6, lane = tid & 63, l15 = lane & 15, qd = lane >> 4;
  const int row0 = blockIdx.x * 64, col0 = blockIdx.y * 64;
  const int xr = tid >> 2, xc = (tid & 3) * 8;
  const int wk = tid >> 3, wc = (tid & 7) * 8;

  f32x4 acc[4] = {{0.f,0.f,0.f,0.f},{0.f,0.f,0.f,0.f},{0.f,0.f,0.f,0.f},{0.f,0.f,0.f,0.f}};

  for (int k0 = 0; k0 < 512; k0 += 32) {
    const size_t idx = (size_t)(row0 + xr)*512 + k0 + xc;
    half8 a0 = *(const half8*)(Ob + idx);
    half8 a1 = *(const half8*)(Ob + OPART + idx);
    *(half8*)&Xs[xr*40 + xc] = a0 + a1;
    f32x4 b0 = *(const f32x4*)(w + (size_t)(k0 + wk)*512 + col0 + wc);
    f32x4 b1 = *(const f32x4*)(w + (size_t)(k0 + wk)*512 + col0 + wc + 4);
#pragma unroll
    for (int j = 0; j < 4; j++) {
      Wt[(wc+j  )*40 + wk] = (_Float16)b0[j];
      Wt[(wc+j+4)*40 + wk] = (_Float16)b1[j];
    }
    __syncthreads();
    half8 af = *(const half8*)&Xs[(wv*16 + l15)*40 + qd*8];
#pragma unroll
    for (int ct = 0; ct < 4; ct++) {
      half8 bf = *(const half8*)&Wt[(ct*16 + l15)*40 + qd*8];
      acc[ct] = MFMA32(af, bf, acc[ct]);
    }
    __syncthreads();
  }
#pragma unroll
  for (int ct = 0; ct < 4; ct++) {
    const int c = col0 + ct*16 + l15;
    const float bv = bias[c];
#pragma unroll
    for (int i = 0; i < 4; i++) {
      const int row = row0 + wv*16 + qd*4 + i;
      out[(size_t)row*512 + c] = acc[ct][i] + bv;
    }
  }
}

// ---------------------------------------------------------------------------
extern "C" void kernel_launch(void* const* d_in, const int* in_sizes, int n_in,
                              void* d_out, int out_size, void* d_ws, size_t ws_size,
                              hipStream_t stream)
{
  (void)in_sizes; (void)n_in; (void)out_size;
  const float* x     = (const float*)d_in[0];
  const float* w_qkv = (const float*)d_in[1];
  const float* b_qkv = (const float*)d_in[2];
  const float* th1   = (const float*)d_in[3];
  const float* th2   = (const float*)d_in[4];
  const float* w_out = (const float*)d_in[5];
  const float* b_out = (const float*)d_in[6];
  float* out = (float*)d_out;

  char* ws = (char*)d_ws;
  _Float16* Qh   = (_Float16*)(ws + QH_OFF);
  _Float16* Kh   = (_Float16*)(ws + KH_OFF);
  _Float16* Vt   = (_Float16*)(ws + VT_OFF);
  float*    Lsum = (float*)   (ws + LS_OFF);
  _Float16* Obuf = (_Float16*)(ws + O_OFF);
  // Xf/Wtf alias the Obuf region (qkv consumes them before pass2 writes O)
  _Float16* Xf   = (_Float16*)(ws + O_OFF);
  _Float16* Wtf  = (_Float16*)(ws + O_OFF + ((size_t)8 << 20));
  if (ws_size < ((size_t)41 << 20)) return;  // need 41 MB scratch

  k_cvtx <<<dim3(4096),    256, 0, stream>>>(x, Xf);
  k_cvtw <<<dim3(16, 48),  256, 0, stream>>>(w_qkv, Wtf);
  k_qkv  <<<dim3(128, 24), 256, 0, stream>>>(Xf, Wtf, b_qkv, Qh, Kh, Vt);
  k_pass1<<<dim3(512),     512, 0, stream>>>(Qh, Kh, th1, Lsum);
  k_pass2<<<dim3(512),     512, 0, stream>>>(Qh, Kh, Vt, Lsum, th1, th2, Obuf);
  k_oproj<<<dim3(128, 8),  256, 0, stream>>>(Obuf, w_out, b_out, out);
}

// Round 15
// 299.003 us; speedup vs baseline: 1.0458x; 1.0143x over previous
//
#include <hip/hip_runtime.h>

typedef _Float16 half8  __attribute__((ext_vector_type(8)));
typedef _Float16 half4  __attribute__((ext_vector_type(4)));
typedef float    f32x4  __attribute__((ext_vector_type(4)));

#define MFMA32(a,b,c) __builtin_amdgcn_mfma_f32_16x16x32_f16(a,b,c,0,0,0)
#define MFMA16(a,b,c) __builtin_amdgcn_mfma_f32_16x16x16f16(a,b,c,0,0,0)

#if __has_builtin(__builtin_amdgcn_exp2f)
#define EXP2F(x) __builtin_amdgcn_exp2f(x)
#else
#define EXP2F(x) exp2f(x)
#endif

// Async global->LDS, 16B/lane, dest = wave-uniform base + lane*16.
#define GLOAD16(gp, lp) __builtin_amdgcn_global_load_lds(                      \
    (const __attribute__((address_space(1))) void*)(gp),                       \
    (__attribute__((address_space(3))) void*)(lp), 16, 0, 0)

// scale = DH^-0.5 = 1/8, folded together with log2(e) into Q so softmax uses exp2.
static constexpr float SCALE_LOG2E = 0.18033688011112042f;

static constexpr size_t QH_OFF = 0;
static constexpr size_t KH_OFF = (size_t)8  << 20;
static constexpr size_t VT_OFF = (size_t)16 << 20;
static constexpr size_t LS_OFF = (size_t)24 << 20;
static constexpr size_t O_OFF  = (size_t)25 << 20;
static constexpr size_t LPART  = (size_t)4*8*2048;   // floats per m-half L partial
static constexpr size_t OPART  = (size_t)8192*512;   // halves per O partial

// ROUND-14/15 tr-read status: corrected 8B/lane addressing brought absmax
// 1.45e-2 -> 6.1e-4. Magnitude analysis: the residual is an m-COLUMN
// permutation sigma(l15) inside each 4x16 pool (s-mapping correct — an
// s-permutation would corrupt L and give percent-level error). Pass1's
// L = sum over ALL m is invariant under any qd-uniform m-bijection, so
// tr-read is provably safe in PASS1 ONLY. Pass2 needs exact m-pairing for
// PV -> reverted to the round-8 verified scalar-read path.
static constexpr int SB_A = 272;   // pass1 Sb: [16s][16m] tiles, A-stride 272
// Pass2 Sb/Wb: round-8 verified layout (GS=340, inner stride 20).
// Rounds 10/11 alternatives both regressed despite floor-predicting models.
static constexpr int GS = 340;

// ---------------------------------------------------------------------------
// K0a: X fp32 -> f16.  grid 4096 x 256 threads, 4 elems/thread.
// ---------------------------------------------------------------------------
__global__ __launch_bounds__(256)
void k_cvtx(const float* __restrict__ x, _Float16* __restrict__ xf)
{
  const size_t i = ((size_t)blockIdx.x*256 + threadIdx.x)*4;
  f32x4 v = *(const f32x4*)(x + i);
  half4 h;
#pragma unroll
  for (int j = 0; j < 4; j++) h[j] = (_Float16)v[j];
  *(half4*)(xf + i) = h;
}

// ---------------------------------------------------------------------------
// K0b: W fp32 [512k][1536c] -> f16 transposed Wt [1536c][512k]. LDS-tiled.
// ---------------------------------------------------------------------------
__global__ __launch_bounds__(256)
void k_cvtw(const float* __restrict__ w, _Float16* __restrict__ wt)
{
  __shared__ _Float16 T[32][36];
  const int kt = blockIdx.x, ct = blockIdx.y;
  const int r = threadIdx.x >> 3, c4 = (threadIdx.x & 7)*4;
  f32x4 v = *(const f32x4*)(w + (size_t)(kt*32 + r)*1536 + ct*32 + c4);
#pragma unroll
  for (int j = 0; j < 4; j++) T[r][c4 + j] = (_Float16)v[j];
  __syncthreads();
  half4 o;
#pragma unroll
  for (int j = 0; j < 4; j++) o[j] = T[c4 + j][r];
  *(half4*)(wt + (size_t)(ct*32 + r)*512 + kt*32 + c4) = o;
}

// ---------------------------------------------------------------------------
// K1: qkv projection, async-staged all-f16. C[8192,1536] = Xf @ Wt^T + b.
// ---------------------------------------------------------------------------
__global__ __launch_bounds__(256)
void k_qkv(const _Float16* __restrict__ xf, const _Float16* __restrict__ wt,
           const float* __restrict__ bias, _Float16* __restrict__ Qh,
           _Float16* __restrict__ Kh, _Float16* __restrict__ Vt)
{
  __shared__ __align__(16) _Float16 Xs[2048];   // 64 rows x 32 k
  __shared__ __align__(16) _Float16 Ws[2048];   // 64 cols x 32 k
  const int tid = threadIdx.x;
  const int wv = tid >> 6, lane = tid & 63, l15 = lane & 15, qd = lane >> 4;
  const int row0 = blockIdx.x * 64, col0 = blockIdx.y * 64;

  const int sslot = wv*64 + lane;
  const int sr = sslot >> 2, so = (sslot & 3) ^ ((sr >> 1) & 3);

  f32x4 acc[4] = {{0.f,0.f,0.f,0.f},{0.f,0.f,0.f,0.f},{0.f,0.f,0.f,0.f},{0.f,0.f,0.f,0.f}};

  for (int k0 = 0; k0 < 512; k0 += 32) {
    GLOAD16(xf + (size_t)(row0 + sr)*512 + k0 + so*8, &Xs[wv*512]);
    GLOAD16(wt + (size_t)(col0 + sr)*512 + k0 + so*8, &Ws[wv*512]);
    __syncthreads();
    const int ra = wv*16 + l15;
    half8 af = *(const half8*)&Xs[(ra*4 + (qd ^ ((ra >> 1) & 3)))*8];
#pragma unroll
    for (int ct = 0; ct < 4; ct++) {
      const int rb = ct*16 + l15;
      half8 bf = *(const half8*)&Ws[(rb*4 + (qd ^ ((rb >> 1) & 3)))*8];
      acc[ct] = MFMA32(af, bf, acc[ct]);
    }
    __syncthreads();
  }
#pragma unroll
  for (int ct = 0; ct < 4; ct++) {
    const int c = col0 + ct*16 + l15;
    const int sec = c >> 9, hh = (c >> 6) & 7, d = c & 63;
    const float bv = bias[c];
#pragma unroll
    for (int i = 0; i < 4; i++) {
      const int row = row0 + wv*16 + qd*4 + i;
      const int bb = row >> 11, n = row & 2047;
      float v = acc[ct][i] + bv;
      if (sec == 0)
        Qh[((size_t)((bb*8 + hh)*2048 + n))*64 + d] = (_Float16)(v * SCALE_LOG2E);
      else if (sec == 1)
        Kh[((size_t)((bb*8 + hh)*2048 + n))*64 + d] = (_Float16)v;
      else
        Vt[((size_t)((bb*8 + hh)*64 + d))*2048 + n] = (_Float16)v;
    }
  }
}

// ---------------------------------------------------------------------------
// K2: pass 1 — softmax denominators over an m-half. Grid 512 = 64nt x (4b x 2mh).
// Round-8 structure + Sb retiled for ds_read_b64_tr_b16. Pass1 is invariant
// to the tr-read's m-column permutation (L sums all 16 m), so this is safe
// even though the exact column order sigma is unknown (round-14 evidence).
// ---------------------------------------------------------------------------
__global__ __launch_bounds__(512, 4)
void k_pass1(const _Float16* __restrict__ Qh, const _Float16* __restrict__ Kh,
             const float* __restrict__ th1, float* __restrict__ Lsum)
{
  __shared__ __align__(16) _Float16 KB[8][1024];     // 16384 B
  __shared__ __align__(16) _Float16 Sb[2][2][2176];  // 17408 B
  const int tid = threadIdx.x;
  const int wv = tid >> 6, lane = tid & 63, l15 = lane & 15, qd = lane >> 4;
  const int s = blockIdx.x & 7, nt = blockIdx.x >> 3;
  const int b = s >> 1, mh = s & 1;
  const int n0 = nt << 5;
  const _Float16* kbase = Kh + ((size_t)((b*8 + wv)*2048 + mh*1024))*64;

  half4 a1f;
#pragma unroll
  for (int j = 0; j < 4; j++)
    a1f[j] = ((l15 >> 3) == (qd >> 1)) ? (_Float16)th1[(l15 & 7)*8 + (qd & 1)*4 + j]
                                       : (_Float16)0.f;

  half8 qf[2][2];
#pragma unroll
  for (int t = 0; t < 2; t++) {
    const _Float16* qp = Qh + ((size_t)((b*8 + wv)*2048 + n0 + t*16 + l15))*64 + qd*8;
    qf[t][0] = *(const half8*)qp;
    qf[t][1] = *(const half8*)(qp + 32);
  }

  auto issueK = [&](int it) {
#pragma unroll
    for (int j = 0; j < 2; j++) {
      const int bk = j*64 + lane;
      const int m = bk >> 3, c = bk & 7;
      const int cp = c ^ (m & 7);
      GLOAD16(kbase + (size_t)(it*16 + m)*64 + cp*8, &KB[wv][j*512]);
    }
  };
  // write: one b64 per t into the [16s][16m] tile of A=l15>>1
  auto qk_to_sb = [&](int buf) {
    half8 ka0 = *(const half8*)&KB[wv][l15*64 + ((qd       ^ (l15 & 7))*8)];
    half8 ka1 = *(const half8*)&KB[wv][l15*64 + (((4 + qd) ^ (l15 & 7))*8)];
#pragma unroll
    for (int t = 0; t < 2; t++) {
      f32x4 a = {0.f,0.f,0.f,0.f};
      a = MFMA32(ka0, qf[t][0], a);
      a = MFMA32(ka1, qf[t][1], a);
      half4 s4;
#pragma unroll
      for (int i = 0; i < 4; i++) s4[i] = (_Float16)a[i];
      *(half4*)&Sb[buf][t][(l15 >> 1)*SB_A + (wv + 8*(l15 & 1))*16 + qd*4] = s4;
    }
  };
  // HW transpose read: per-lane addr = tile + qd*64 + l15*4 halves (8B/lane).
  // Delivers s=4qd+j correctly; m-column may be a permuted l15 (harmless here).
  auto sb_tr = [&](const _Float16* p) -> half4 {
    half4 r;
    asm volatile("ds_read_b64_tr_b16 %0, %1"
                 : "=v"(r)
                 : "v"((const __attribute__((address_space(3))) _Float16*)p));
    return r;
  };

  float lacc[2][4];
#pragma unroll
  for (int t = 0; t < 2; t++)
#pragma unroll
    for (int i = 0; i < 4; i++) lacc[t][i] = 0.f;

  issueK(0);
  __syncthreads();
  for (int it = 0; it <= 64; it++) {
    if (it < 64) {
      qk_to_sb(it & 1);
      if (it + 1 < 64) issueK(it + 1);
    }
    if (it >= 1) {
      const int buf = (it - 1) & 1;
      half4 b1[2];
      b1[0] = sb_tr(&Sb[buf][0][wv*SB_A + qd*64 + l15*4]);
      b1[1] = sb_tr(&Sb[buf][1][wv*SB_A + qd*64 + l15*4]);
      asm volatile("s_waitcnt lgkmcnt(0)" ::: "memory");
      __builtin_amdgcn_sched_barrier(0);
#pragma unroll
      for (int t = 0; t < 2; t++) {
        f32x4 c1 = MFMA16(a1f, b1[t], ((f32x4){0.f,0.f,0.f,0.f}));
#pragma unroll
        for (int i = 0; i < 4; i++) lacc[t][i] += EXP2F(c1[i]);
      }
    }
    __syncthreads();
  }

#pragma unroll
  for (int t = 0; t < 2; t++)
#pragma unroll
    for (int i = 0; i < 4; i++) {
      float v = lacc[t][i];
      v += __shfl_xor(v, 1); v += __shfl_xor(v, 2);
      v += __shfl_xor(v, 4); v += __shfl_xor(v, 8);
      lacc[t][i] = v;
    }
  if (l15 == 0) {
#pragma unroll
    for (int t = 0; t < 2; t++)
#pragma unroll
      for (int i = 0; i < 4; i++) {
        const int n = n0 + t*16 + wv*2 + (qd >> 1);
        const int g = (qd & 1)*4 + i;
        Lsum[(size_t)mh*LPART + (size_t)(b*8 + g)*2048 + n] = lacc[t][i];
      }
  }
}

// ---------------------------------------------------------------------------
// K3: pass 2 over an m-half. ROUND-8 VERIFIED CODE, byte-identical (scalar
// Sb reads; Sb/Wb GS=340 stride-20). tr-read NOT used here: PV needs exact
// m-pairing and the tr-read's column permutation is unidentified.
// ---------------------------------------------------------------------------
__global__ __launch_bounds__(512, 4)
void k_pass2(const _Float16* __restrict__ Qh, const _Float16* __restrict__ Kh,
             const _Float16* __restrict__ Vt, const float* __restrict__ Lsum,
             const float* __restrict__ th1, const float* __restrict__ th2,
             _Float16* __restrict__ Obuf)
{
  __shared__ __align__(16) _Float16 KB[8][1024];     // 16384 B
  __shared__ __align__(16) _Float16 VB[8][1024];     // 16384 B [wv][slot=mh2*64+d]
  __shared__ __align__(16) _Float16 Sb[2][2][2704];  // 21632 B
  __shared__ __align__(16) _Float16 Wb[2][2][2704];  // 21632 B  (total 76032 B)
  const int tid = threadIdx.x;
  const int wv = tid >> 6, lane = tid & 63, l15 = lane & 15, qd = lane >> 4;
  const int s = blockIdx.x & 7, nt = blockIdx.x >> 3;
  const int b = s >> 1, mh = s & 1;
  const int n0 = nt << 5;
  const _Float16* kbase = Kh + ((size_t)((b*8 + wv)*2048 + mh*1024))*64;
  const _Float16* vbase = Vt + (size_t)(b*8 + wv)*64*2048 + mh*1024;

  half4 a1f, b2f;
#pragma unroll
  for (int j = 0; j < 4; j++) {
    const bool diag = ((l15 >> 3) == (qd >> 1));
    a1f[j] = diag ? (_Float16)th1[(l15 & 7)*8 + (qd & 1)*4 + j] : (_Float16)0.f;
    b2f[j] = diag ? (_Float16)th2[(l15 & 7)*8 + (qd & 1)*4 + j] : (_Float16)0.f;
  }

  // softmax seed, hoisted to registers (constant per lane across all iters)
  f32x4 cs[2];
#pragma unroll
  for (int t = 0; t < 2; t++)
#pragma unroll
    for (int i = 0; i < 4; i++) {
      const int n = n0 + t*16 + wv*2 + (qd >> 1);
      const int g = (qd & 1)*4 + i;
      const size_t off = (size_t)(b*8 + g)*2048 + n;
      cs[t][i] = -__log2f(Lsum[off] + Lsum[off + LPART]);
    }

  half8 qf[2][2];
#pragma unroll
  for (int t = 0; t < 2; t++) {
    const _Float16* qp = Qh + ((size_t)((b*8 + wv)*2048 + n0 + t*16 + l15))*64 + qd*8;
    qf[t][0] = *(const half8*)qp;
    qf[t][1] = *(const half8*)(qp + 32);
  }

  auto issueK = [&](int it) {
#pragma unroll
    for (int j = 0; j < 2; j++) {
      const int bk = j*64 + lane;
      const int m = bk >> 3, c = bk & 7;
      const int cp = c ^ (m & 7);
      GLOAD16(kbase + (size_t)(it*16 + m)*64 + cp*8, &KB[wv][j*512]);
    }
  };
  // VB slots: issue j covers slots j*64+lane = (mhalf=j, d=lane)
  auto issueV = [&](int it) {
#pragma unroll
    for (int j = 0; j < 2; j++)
      GLOAD16(vbase + (size_t)lane*2048 + it*16 + j*8, &VB[wv][j*512]);
  };
  // swapped layout: one b64 write per t at [A=l15>>1][s=wv+8*(l15&1)][C=qd*4]
  auto qk_to_sb = [&](int buf) {
    half8 ka0 = *(const half8*)&KB[wv][l15*64 + ((qd       ^ (l15 & 7))*8)];
    half8 ka1 = *(const half8*)&KB[wv][l15*64 + (((4 + qd) ^ (l15 & 7))*8)];
#pragma unroll
    for (int t = 0; t < 2; t++) {
      f32x4 a = {0.f,0.f,0.f,0.f};
      a = MFMA32(ka0, qf[t][0], a);
      a = MFMA32(ka1, qf[t][1], a);
      half4 s4;
#pragma unroll
      for (int i = 0; i < 4; i++) s4[i] = (_Float16)a[i];
      *(half4*)&Sb[buf][t][(l15 >> 1)*GS + (wv + 8*(l15 & 1))*20 + qd*4] = s4;
    }
  };

  f32x4 og[2][4];
#pragma unroll
  for (int t = 0; t < 2; t++)
#pragma unroll
    for (int dt = 0; dt < 4; dt++)
      og[t][dt] = (f32x4){0.f,0.f,0.f,0.f};

  issueK(0);
  __syncthreads();

  for (int it = 0; it <= 65; it++) {
    if (it < 64) {
      qk_to_sb(it & 1);
      if (it + 1 < 64) issueK(it + 1);
    }

    if (it >= 1 && it <= 64) {
      const int buf = (it - 1) & 1;
#pragma unroll
      for (int t = 0; t < 2; t++) {
        half4 b1;
#pragma unroll
        for (int j = 0; j < 4; j++)
          b1[j] = Sb[buf][t][wv*GS + (qd*4 + j)*20 + l15];
        f32x4 c1 = MFMA16(a1f, b1, cs[t]);
        half4 a2;
#pragma unroll
        for (int i = 0; i < 4; i++) a2[i] = (_Float16)EXP2F(c1[i]);
        f32x4 c2 = MFMA16(a2, b2f, ((f32x4){0.f,0.f,0.f,0.f}));
        half4 w4;
#pragma unroll
        for (int i = 0; i < 4; i++) w4[i] = (_Float16)c2[i];
        *(half4*)&Wb[buf][t][(l15 & 7)*GS + (wv*2 + (l15 >> 3))*20 + qd*4] = w4;
      }
    }
    if (it >= 2) {
      const int buf = (it - 2) & 1;
      half4 vb[4];
#pragma unroll
      for (int dt = 0; dt < 4; dt++)
        vb[dt] = *(const half4*)&VB[wv][((qd >> 1)*64 + dt*16 + l15)*8 + (qd & 1)*4];
#pragma unroll
      for (int t = 0; t < 2; t++) {
        half4 af = *(const half4*)&Wb[buf][t][wv*GS + l15*20 + qd*4];
#pragma unroll
        for (int dt = 0; dt < 4; dt++)
          og[t][dt] = MFMA16(af, vb[dt], og[t][dt]);
      }
    }
    if (it >= 1 && it <= 64) issueV(it - 1);   // after VB reads (in-wave WAR safe)
    __syncthreads();
  }

  // epilogue: og[t][dt][i] -> (n = n0+t*16+qd*4+i, col = wv*64 + dt*16 + l15)
  _Float16* Op = Obuf + (size_t)mh * OPART + ((size_t)(b*2048 + n0))*512;
#pragma unroll
  for (int t = 0; t < 2; t++)
#pragma unroll
    for (int dt = 0; dt < 4; dt++)
#pragma unroll
      for (int i = 0; i < 4; i++)
        Op[(size_t)(t*16 + qd*4 + i)*512 + wv*64 + dt*16 + l15] = (_Float16)og[t][dt][i];
}

// ---------------------------------------------------------------------------
// K4: output projection summing 2 partial O buffers.
// out[8192,512] = (O0+O1) @ w_out[512,512] + b_out (fp32 out)
// ---------------------------------------------------------------------------
__global__ __launch_bounds__(256)
void k_oproj(const _Float16* __restrict__ Ob, const float* __restrict__ w,
             const float* __restrict__ bias, float* __restrict__ out)
{
  __shared__ __align__(16) _Float16 Xs[64*40];
  __shared__ __align__(16) _Float16 Wt[64*40];
  const int tid = threadIdx.x;
  const int wv = tid >> 6, lane = tid & 63, l15 = lane & 15, qd = lane >> 4;
  const int row0 = blockIdx.x * 64, col0 = blockIdx.y * 64;
  const int xr = tid >> 2, xc = (tid & 3) * 8;
  const int wk = tid >> 3, wc = (tid & 7) * 8;

  f32x4 acc[4] = {{0.f,0.f,0.f,0.f},{0.f,0.f,0.f,0.f},{0.f,0.f,0.f,0.f},{0.f,0.f,0.f,0.f}};

  for (int k0 = 0; k0 < 512; k0 += 32) {
    const size_t idx = (size_t)(row0 + xr)*512 + k0 + xc;
    half8 a0 = *(const half8*)(Ob + idx);
    half8 a1 = *(const half8*)(Ob + OPART + idx);
    *(half8*)&Xs[xr*40 + xc] = a0 + a1;
    f32x4 b0 = *(const f32x4*)(w + (size_t)(k0 + wk)*512 + col0 + wc);
    f32x4 b1 = *(const f32x4*)(w + (size_t)(k0 + wk)*512 + col0 + wc + 4);
#pragma unroll
    for (int j = 0; j < 4; j++) {
      Wt[(wc+j  )*40 + wk] = (_Float16)b0[j];
      Wt[(wc+j+4)*40 + wk] = (_Float16)b1[j];
    }
    __syncthreads();
    half8 af = *(const half8*)&Xs[(wv*16 + l15)*40 + qd*8];
#pragma unroll
    for (int ct = 0; ct < 4; ct++) {
      half8 bf = *(const half8*)&Wt[(ct*16 + l15)*40 + qd*8];
      acc[ct] = MFMA32(af, bf, acc[ct]);
    }
    __syncthreads();
  }
#pragma unroll
  for (int ct = 0; ct < 4; ct++) {
    const int c = col0 + ct*16 + l15;
    const float bv = bias[c];
#pragma unroll
    for (int i = 0; i < 4; i++) {
      const int row = row0 + wv*16 + qd*4 + i;
      out[(size_t)row*512 + c] = acc[ct][i] + bv;
    }
  }
}

// ---------------------------------------------------------------------------
extern "C" void kernel_launch(void* const* d_in, const int* in_sizes, int n_in,
                              void* d_out, int out_size, void* d_ws, size_t ws_size,
                              hipStream_t stream)
{
  (void)in_sizes; (void)n_in; (void)out_size;
  const float* x     = (const float*)d_in[0];
  const float* w_qkv = (const float*)d_in[1];
  const float* b_qkv = (const float*)d_in[2];
  const float* th1   = (const float*)d_in[3];
  const float* th2   = (const float*)d_in[4];
  const float* w_out = (const float*)d_in[5];
  const float* b_out = (const float*)d_in[6];
  float* out = (float*)d_out;

  char* ws = (char*)d_ws;
  _Float16* Qh   = (_Float16*)(ws + QH_OFF);
  _Float16* Kh   = (_Float16*)(ws + KH_OFF);
  _Float16* Vt   = (_Float16*)(ws + VT_OFF);
  float*    Lsum = (float*)   (ws + LS_OFF);
  _Float16* Obuf = (_Float16*)(ws + O_OFF);
  // Xf/Wtf alias the Obuf region (qkv consumes them before pass2 writes O)
  _Float16* Xf   = (_Float16*)(ws + O_OFF);
  _Float16* Wtf  = (_Float16*)(ws + O_OFF + ((size_t)8 << 20));
  if (ws_size < ((size_t)41 << 20)) return;  // need 41 MB scratch

  k_cvtx <<<dim3(4096),    256, 0, stream>>>(x, Xf);
  k_cvtw <<<dim3(16, 48),  256, 0, stream>>>(w_qkv, Wtf);
  k_qkv  <<<dim3(128, 24), 256, 0, stream>>>(Xf, Wtf, b_qkv, Qh, Kh, Vt);
  k_pass1<<<dim3(512),     512, 0, stream>>>(Qh, Kh, th1, Lsum);
  k_pass2<<<dim3(512),     512, 0, stream>>>(Qh, Kh, Vt, Lsum, th1, th2, Obuf);
  k_oproj<<<dim3(128, 8),  256, 0, stream>>>(Obuf, w_out, b_out, out);
}